// Round 1
// baseline (169.700 us; speedup 1.0000x reference)
//
#include <hip/hip_runtime.h>
#include <stdint.h>

#define NN 16384
#define DD 128
#define KT 64      // k-tile rows
#define WAVES 4    // waves per block in k_attn
#define QW 32      // q rows per wave
#define QB 128     // q rows per block

typedef __bf16 bf16x8 __attribute__((ext_vector_type(8)));
typedef float f32x4 __attribute__((ext_vector_type(4)));

using gv = __attribute__((address_space(1))) const void;
using lv = __attribute__((address_space(3))) void;

__device__ __forceinline__ uint16_t f2bf(float f) {
  uint32_t u = __builtin_bit_cast(uint32_t, f);
  u += 0x7fffu + ((u >> 16) & 1u);   // RNE
  return (uint16_t)(u >> 16);
}

// K1: row L2-norms -> normx (bf16 bits). One wave per row, 2 cols/lane.
__global__ void k_norm(const float* __restrict__ x, uint16_t* __restrict__ nx) {
  const int wave = threadIdx.x >> 6, lane = threadIdx.x & 63;
  const int row = blockIdx.x * 4 + wave;
  const float2 v = *reinterpret_cast<const float2*>(x + (size_t)row * DD + 2 * lane);
  float ss = v.x * v.x + v.y * v.y;
#pragma unroll
  for (int m = 1; m < 64; m <<= 1) ss += __shfl_xor(ss, m);
  const float rn = 1.0f / fmaxf(sqrtf(ss), 1e-12f);
  uint32_t w = (uint32_t)f2bf(v.x * rn) | ((uint32_t)f2bf(v.y * rn) << 16);
  *reinterpret_cast<uint32_t*>(nx + (size_t)row * DD + 2 * lane) = w;
}

// K1b: transpose x (fp32 [N][D]) -> xT (bf16 bits [D][N]) via 64x64 LDS tiles.
__global__ void k_transpose(const float* __restrict__ x, uint16_t* __restrict__ xT) {
  __shared__ uint16_t tile[64 * 65];
  const int r0 = (blockIdx.x >> 1) * 64;  // N-block
  const int c0 = (blockIdx.x & 1) * 64;   // D-block
  const int t = threadIdx.x;
#pragma unroll
  for (int e = 0; e < 16; ++e) {
    int idx = e * 256 + t;
    int r = idx >> 6, c = idx & 63;
    tile[r * 65 + c] = f2bf(x[(size_t)(r0 + r) * DD + c0 + c]);
  }
  __syncthreads();
#pragma unroll
  for (int e = 0; e < 16; ++e) {
    int idx = e * 256 + t;
    int cc = idx >> 6, rr = idx & 63;
    xT[(size_t)(c0 + cc) * NN + r0 + rr] = tile[rr * 65 + cc];
  }
}

// K2: flash attention (no-max softmax: scores bounded by 1). Writes partial
// O = sum(exp(S)*V) and L = sum(exp(S)) per k-split (exact; combine = add).
__global__ __launch_bounds__(256, 2) void k_attn(
    const uint16_t* __restrict__ nx, const uint16_t* __restrict__ xT,
    float* __restrict__ Op, float* __restrict__ Lp, int nsplit) {
  __shared__ alignas(16) uint16_t Kb[2][KT * DD];   // 2 x 16 KiB, swizzled rows (256B)
  __shared__ alignas(16) uint16_t Vb[2][DD * KT];   // 2 x 16 KiB  V^T, swizzled rows (128B)
  __shared__ alignas(16) uint16_t Pb[WAVES][QW * KT]; // 4 x 4 KiB, per-wave private

  const int tid = threadIdx.x;
  const int wave = tid >> 6;
  const int lane = tid & 63;
  const int lrow = lane & 15;
  const int lgrp = lane >> 4;

  const int qblock = blockIdx.x;
  const int split = blockIdx.y;
  const int ntiles = (NN / KT) / nsplit;
  const int tstart = split * ntiles;
  const int qbase = qblock * QB + wave * QW;

  // Q fragments in registers: A-frag = row (lane&15), 8 contig d at 8*(lane>>4)
  bf16x8 qf[2][4];
#pragma unroll
  for (int qt = 0; qt < 2; ++qt)
#pragma unroll
    for (int c = 0; c < 4; ++c)
      qf[qt][c] = *reinterpret_cast<const bf16x8*>(
          nx + (size_t)(qbase + qt * 16 + lrow) * DD + c * 32 + lgrp * 8);

  f32x4 o[2][8];
  float ls[2][4];
#pragma unroll
  for (int qt = 0; qt < 2; ++qt) {
#pragma unroll
    for (int dt = 0; dt < 8; ++dt) o[qt][dt] = (f32x4){0.f, 0.f, 0.f, 0.f};
#pragma unroll
    for (int r = 0; r < 4; ++r) ls[qt][r] = 0.f;
  }

  const char* nxb = reinterpret_cast<const char*>(nx);
  const char* xtb = reinterpret_cast<const char*>(xT);

  // Stage K-tile (rows of normx) and V^T-tile (rows of xT) with inverse-swizzled
  // global source; global_load_lds writes LDS linearly (base + lane*16).
  auto stage = [&](int tt, int buf) {
    const int k0 = tt * KT;
#pragma unroll
    for (int jj = 0; jj < 4; ++jj) {
      const int j = wave * 4 + jj;
      const int A = j * 1024 + lane * 16;
      const int row = A >> 8, b = A & 255;
      const char* src = nxb + (size_t)(k0 + row) * 256 + (b ^ ((row & 7) << 4));
      __builtin_amdgcn_global_load_lds((gv*)src,
          (lv*)(reinterpret_cast<char*>(&Kb[buf][0]) + j * 1024), 16, 0, 0);
    }
#pragma unroll
    for (int jj = 0; jj < 4; ++jj) {
      const int j = wave * 4 + jj;
      const int A = j * 1024 + lane * 16;
      const int d = A >> 7, b = A & 127;
      const char* src = xtb + (size_t)d * (NN * 2) + k0 * 2 + (b ^ ((d & 7) << 4));
      __builtin_amdgcn_global_load_lds((gv*)src,
          (lv*)(reinterpret_cast<char*>(&Vb[buf][0]) + j * 1024), 16, 0, 0);
    }
  };

  stage(tstart, 0);
  asm volatile("s_waitcnt vmcnt(0)" ::: "memory");
  __syncthreads();

  for (int t = 0; t < ntiles; ++t) {
    if (t + 1 < ntiles) stage(tstart + t + 1, (t + 1) & 1);
    const int buf = t & 1;
    const char* kb = reinterpret_cast<const char*>(&Kb[buf][0]);
    const char* vb = reinterpret_cast<const char*>(&Vb[buf][0]);
    char* pb = reinterpret_cast<char*>(&Pb[wave][0]);

    // ---- QK^T: S[qt][n] (16x16 tiles), K-frags shared across qt ----
    f32x4 s[2][4];
#pragma unroll
    for (int qt = 0; qt < 2; ++qt)
#pragma unroll
      for (int n = 0; n < 4; ++n) s[qt][n] = (f32x4){0.f, 0.f, 0.f, 0.f};
#pragma unroll
    for (int n = 0; n < 4; ++n) {
#pragma unroll
      for (int c = 0; c < 4; ++c) {
        const int row = n * 16 + lrow;
        const int byt = (c * 64 + lgrp * 16) ^ ((row & 7) << 4);
        const bf16x8 kf = *reinterpret_cast<const bf16x8*>(kb + row * 256 + byt);
        s[0][n] = __builtin_amdgcn_mfma_f32_16x16x32_bf16(qf[0][c], kf, s[0][n], 0, 0, 0);
        s[1][n] = __builtin_amdgcn_mfma_f32_16x16x32_bf16(qf[1][c], kf, s[1][n], 0, 0, 0);
      }
    }

    // ---- P = exp(S) (scores bounded by ~1: no max needed), row-sum partials,
    //      bf16 P into per-wave swizzled LDS ----
#pragma unroll
    for (int qt = 0; qt < 2; ++qt)
#pragma unroll
      for (int n = 0; n < 4; ++n)
#pragma unroll
        for (int r = 0; r < 4; ++r) {
          const float p = __expf(s[qt][n][r]);
          ls[qt][r] += p;
          const int row = qt * 16 + 4 * lgrp + r;  // C layout: row = 4*(lane>>4)+reg
          const int byt = ((n * 16 + lrow) * 2) ^ ((row & 7) << 4);
          *reinterpret_cast<uint16_t*>(pb + row * 128 + byt) = f2bf(p);
        }

    // ---- PV: O[qt][dt] += P[qt] * V ----
#pragma unroll
    for (int kc = 0; kc < 2; ++kc) {
      bf16x8 pf[2];
#pragma unroll
      for (int qt = 0; qt < 2; ++qt) {
        const int row = qt * 16 + lrow;
        const int byt = (kc * 64 + lgrp * 16) ^ ((row & 7) << 4);
        pf[qt] = *reinterpret_cast<const bf16x8*>(pb + row * 128 + byt);
      }
#pragma unroll
      for (int dt = 0; dt < 8; ++dt) {
        const int row = dt * 16 + lrow;
        const int byt = (kc * 64 + lgrp * 16) ^ ((row & 7) << 4);
        const bf16x8 vf = *reinterpret_cast<const bf16x8*>(vb + row * 128 + byt);
        o[0][dt] = __builtin_amdgcn_mfma_f32_16x16x32_bf16(pf[0], vf, o[0][dt], 0, 0, 0);
        o[1][dt] = __builtin_amdgcn_mfma_f32_16x16x32_bf16(pf[1], vf, o[1][dt], 0, 0, 0);
      }
    }

    asm volatile("s_waitcnt vmcnt(0)" ::: "memory");
    __syncthreads();
  }

  // Row-sum reduce over the 16 columns held by lanes lrow=0..15
#pragma unroll
  for (int qt = 0; qt < 2; ++qt)
#pragma unroll
    for (int r = 0; r < 4; ++r) {
      float v = ls[qt][r];
      v += __shfl_xor(v, 1);
      v += __shfl_xor(v, 2);
      v += __shfl_xor(v, 4);
      v += __shfl_xor(v, 8);
      ls[qt][r] = v;
    }

  float* Ob = Op + (size_t)split * NN * DD;
#pragma unroll
  for (int qt = 0; qt < 2; ++qt)
#pragma unroll
    for (int dt = 0; dt < 8; ++dt)
#pragma unroll
      for (int r = 0; r < 4; ++r) {
        const int grow = qbase + qt * 16 + 4 * lgrp + r;
        Ob[(size_t)grow * DD + dt * 16 + lrow] = o[qt][dt][r];
      }
  if (lrow == 0) {
#pragma unroll
    for (int qt = 0; qt < 2; ++qt)
#pragma unroll
      for (int r = 0; r < 4; ++r)
        Lp[(size_t)split * NN + qbase + qt * 16 + 4 * lgrp + r] = ls[qt][r];
  }
}

// K3: combine splits, y = 1.5x - 0.5*(O/L), LayerNorm over D, write fp32 out.
__global__ void k_final(const float* __restrict__ x, const float* __restrict__ gamma,
                        const float* __restrict__ beta, const float* __restrict__ Op,
                        const float* __restrict__ Lp, float* __restrict__ out, int nsplit) {
  const int wave = threadIdx.x >> 6, lane = threadIdx.x & 63;
  const int row = blockIdx.x * 4 + wave;
  float o0 = 0.f, o1 = 0.f, lt = 0.f;
  for (int s = 0; s < nsplit; ++s) {
    const float2 v = *reinterpret_cast<const float2*>(
        Op + (size_t)s * NN * DD + (size_t)row * DD + 2 * lane);
    o0 += v.x;
    o1 += v.y;
    lt += Lp[(size_t)s * NN + row];
  }
  const float inv = 1.0f / lt;
  const float2 xv = *reinterpret_cast<const float2*>(x + (size_t)row * DD + 2 * lane);
  float y0 = 1.5f * xv.x - 0.5f * o0 * inv;
  float y1 = 1.5f * xv.y - 0.5f * o1 * inv;
  float sum = y0 + y1;
#pragma unroll
  for (int m = 1; m < 64; m <<= 1) sum += __shfl_xor(sum, m);
  const float mu = sum * (1.0f / 128.0f);
  const float d0 = y0 - mu, d1 = y1 - mu;
  float vs = d0 * d0 + d1 * d1;
#pragma unroll
  for (int m = 1; m < 64; m <<= 1) vs += __shfl_xor(vs, m);
  const float rs = rsqrtf(vs * (1.0f / 128.0f) + 1e-5f);
  const float2 g = *reinterpret_cast<const float2*>(gamma + 2 * lane);
  const float2 b = *reinterpret_cast<const float2*>(beta + 2 * lane);
  float2 ov;
  ov.x = d0 * rs * g.x + b.x;
  ov.y = d1 * rs * g.y + b.y;
  *reinterpret_cast<float2*>(out + (size_t)row * DD + 2 * lane) = ov;
}

extern "C" void kernel_launch(void* const* d_in, const int* in_sizes, int n_in,
                              void* d_out, int out_size, void* d_ws, size_t ws_size,
                              hipStream_t stream) {
  const float* x = (const float*)d_in[0];
  const float* gamma = (const float*)d_in[1];
  const float* beta = (const float*)d_in[2];
  float* out = (float*)d_out;
  char* ws = (char*)d_ws;

  uint16_t* nx = (uint16_t*)ws;                            // 4 MiB bf16 [N][D]
  uint16_t* xT = (uint16_t*)(ws + (size_t)NN * DD * 2);    // 4 MiB bf16 [D][N]
  const size_t base = (size_t)2 * NN * DD * 2;
  const size_t per = (size_t)NN * DD * 4 + (size_t)NN * 4; // per-split O + L

  int nsplit = 1;
  if (ws_size >= base + 4 * per) nsplit = 4;
  else if (ws_size >= base + 2 * per) nsplit = 2;

  float* Op = (float*)(ws + base);
  float* Lp = (float*)(ws + base + (size_t)nsplit * NN * DD * 4);

  k_norm<<<NN / 4, 256, 0, stream>>>(x, nx);
  k_transpose<<<(NN / 64) * (DD / 64), 256, 0, stream>>>(x, xT);
  k_attn<<<dim3(NN / QB, nsplit), 256, 0, stream>>>(nx, xT, Op, Lp, nsplit);
  k_final<<<NN / 4, 256, 0, stream>>>(x, gamma, beta, Op, Lp, out, nsplit);
}

// Round 2
// 159.098 us; speedup vs baseline: 1.0666x; 1.0666x over previous
//
#include <hip/hip_runtime.h>
#include <stdint.h>

#define NN 16384
#define DD 128
#define KT 64      // k-tile rows
#define QB 256     // q rows per block (8 waves x 32)

typedef __bf16 bf16x8 __attribute__((ext_vector_type(8)));
typedef float f32x16 __attribute__((ext_vector_type(16)));
typedef uint32_t u32x4 __attribute__((ext_vector_type(4)));

using gv = __attribute__((address_space(1))) const void;
using lv = __attribute__((address_space(3))) void;

__device__ __forceinline__ uint16_t f2bf(float f) {
  uint32_t u = __builtin_bit_cast(uint32_t, f);
  u += 0x7fffu + ((u >> 16) & 1u);   // RNE
  return (uint16_t)(u >> 16);
}

// K1: row L2-norms -> normx (bf16 bits). One wave per row, 2 cols/lane.
__global__ void k_norm(const float* __restrict__ x, uint16_t* __restrict__ nx) {
  const int wave = threadIdx.x >> 6, lane = threadIdx.x & 63;
  const int row = blockIdx.x * 4 + wave;
  const float2 v = *reinterpret_cast<const float2*>(x + (size_t)row * DD + 2 * lane);
  float ss = v.x * v.x + v.y * v.y;
#pragma unroll
  for (int m = 1; m < 64; m <<= 1) ss += __shfl_xor(ss, m);
  const float rn = 1.0f / fmaxf(sqrtf(ss), 1e-12f);
  uint32_t w = (uint32_t)f2bf(v.x * rn) | ((uint32_t)f2bf(v.y * rn) << 16);
  *reinterpret_cast<uint32_t*>(nx + (size_t)row * DD + 2 * lane) = w;
}

// K1b: transpose x (fp32 [N][D]) -> xT (bf16 bits [D][N]) via 64x64 LDS tiles.
__global__ void k_transpose(const float* __restrict__ x, uint16_t* __restrict__ xT) {
  __shared__ uint16_t tile[64 * 65];
  const int r0 = (blockIdx.x >> 1) * 64;  // N-block
  const int c0 = (blockIdx.x & 1) * 64;   // D-block
  const int t = threadIdx.x;
#pragma unroll
  for (int e = 0; e < 16; ++e) {
    int idx = e * 256 + t;
    int r = idx >> 6, c = idx & 63;
    tile[r * 65 + c] = f2bf(x[(size_t)(r0 + r) * DD + c0 + c]);
  }
  __syncthreads();
#pragma unroll
  for (int e = 0; e < 16; ++e) {
    int idx = e * 256 + t;
    int cc = idx >> 6, rr = idx & 63;
    xT[(size_t)(c0 + cc) * NN + r0 + rr] = tile[rr * 65 + cc];
  }
}

// K2: flash attention, 8 waves x 32 q-rows, 32x32x16 MFMA, swapped QK^T,
// in-register softmax (scores bounded by 1 -> no max tracking), P via
// cvt_pk_bf16 + permlane32_swap. 3-buffer K/V staging with counted vmcnt.
__global__ __launch_bounds__(512, 2) void k_attn(
    const uint16_t* __restrict__ nx, const uint16_t* __restrict__ xT,
    float* __restrict__ Op, float* __restrict__ Lp, int nsplit) {
  __shared__ alignas(16) uint16_t Kb[3][KT * DD];   // 3 x 16 KiB, rows 256B swizzled
  __shared__ alignas(16) uint16_t Vb[3][DD * KT];   // 3 x 16 KiB, V^T rows 128B swizzled

  const int tid = threadIdx.x;
  const int wave = tid >> 6;
  const int lane = tid & 63;
  const int rl = lane & 31;
  const int hi = lane >> 5;
  const int cswz = (16 * hi) ^ ((lane & 7) << 4);  // per-lane column+swizzle bits

  // XCD-aware decomposition: group all q-blocks of one split onto 2 XCDs so
  // the split's K/V working set (2 MiB) stays L2-resident.
  const int id = blockIdx.x;
  int qblock, split;
  if (nsplit == 4) { split = (id & 7) >> 1; qblock = ((id >> 3) << 1) | (id & 1); }
  else { qblock = id & 63; split = id >> 6; }

  const int nt = (NN / KT) / nsplit;
  const int t0s = split * nt;
  const int qw = qblock * QB + wave * 32;

  // Q B-frags: lane holds Qn[qw + (l&31)][dc*16 + 8*hi .. +8]
  bf16x8 q8[8];
#pragma unroll
  for (int dc = 0; dc < 8; ++dc)
    q8[dc] = *reinterpret_cast<const bf16x8*>(
        nx + (size_t)(qw + rl) * DD + dc * 16 + 8 * hi);

  f32x16 o[4];
#pragma unroll
  for (int dt = 0; dt < 4; ++dt)
#pragma unroll
    for (int r = 0; r < 16; ++r) o[dt][r] = 0.f;
  float lsum = 0.f;

  const char* nxb = reinterpret_cast<const char*>(nx);
  const char* xtb = reinterpret_cast<const char*>(xT);

  // Stage K-tile [64][128]bf16 and V^T-tile [128][64]bf16: linear LDS dest,
  // inverse-swizzled global source (rule: both-sides-or-neither).
  auto stage = [&](int tt, int buf) {
    const int k0 = tt * KT;
#pragma unroll
    for (int jj = 0; jj < 2; ++jj) {
      const int j = wave * 2 + jj;
      const int A = j * 1024 + lane * 16;
      {
        const int row = A >> 8, b = A & 255;
        const char* src = nxb + (size_t)(k0 + row) * 256 + (b ^ ((row & 7) << 4));
        __builtin_amdgcn_global_load_lds((gv*)src,
            (lv*)(reinterpret_cast<char*>(&Kb[buf][0]) + j * 1024), 16, 0, 0);
      }
      {
        const int d = A >> 7, b2 = A & 127;
        const char* src = xtb + (size_t)d * (NN * 2) + (size_t)k0 * 2 + (b2 ^ ((d & 7) << 4));
        __builtin_amdgcn_global_load_lds((gv*)src,
            (lv*)(reinterpret_cast<char*>(&Vb[buf][0]) + j * 1024), 16, 0, 0);
      }
    }
  };

  stage(t0s + 0, 0);
  stage(t0s + 1, 1);

  for (int t = 0; t < nt; ++t) {
    __builtin_amdgcn_sched_barrier(0);
    if (t + 1 < nt) asm volatile("s_waitcnt vmcnt(4)" ::: "memory");
    else            asm volatile("s_waitcnt vmcnt(0)" ::: "memory");
    __builtin_amdgcn_s_barrier();
    __builtin_amdgcn_sched_barrier(0);
    if (t + 2 < nt) stage(t0s + t + 2, (t + 2) % 3);

    const int buf = t % 3;
    const char* kb = reinterpret_cast<const char*>(&Kb[buf][0]);
    const char* vb = reinterpret_cast<const char*>(&Vb[buf][0]);

    // ---- swapped QK^T: S^T[k][q], two 32-row k-subtiles, ILP 2 ----
    f32x16 s0, s1;
#pragma unroll
    for (int r = 0; r < 16; ++r) { s0[r] = 0.f; s1[r] = 0.f; }
#pragma unroll
    for (int dc = 0; dc < 8; ++dc) {
      const int byt = (dc * 32) ^ cswz;
      const bf16x8 ka0 = *reinterpret_cast<const bf16x8*>(kb + rl * 256 + byt);
      const bf16x8 ka1 = *reinterpret_cast<const bf16x8*>(kb + 8192 + rl * 256 + byt);
      s0 = __builtin_amdgcn_mfma_f32_32x32x16_bf16(ka0, q8[dc], s0, 0, 0, 0);
      s1 = __builtin_amdgcn_mfma_f32_32x32x16_bf16(ka1, q8[dc], s1, 0, 0, 0);
    }

    // ---- in-register softmax: p = exp(s) (|s|<=1), pack to PV A-frags ----
    // lane holds P[q = l&31][k_local = (reg&3) + 8*(reg>>2) + 4*hi + 32*kt]
    bf16x8 pa[4];
#pragma unroll
    for (int kt = 0; kt < 2; ++kt) {
      float pe[16];
#pragma unroll
      for (int r = 0; r < 16; ++r) {
        const float sv = (kt == 0) ? s0[r] : s1[r];
        pe[r] = __expf(sv);
        lsum += pe[r];
      }
#pragma unroll
      for (int kc = 0; kc < 2; ++kc) {
        uint32_t w0, w1, u0, u1;
        asm("v_cvt_pk_bf16_f32 %0, %1, %2" : "=v"(w0) : "v"(pe[8 * kc + 0]), "v"(pe[8 * kc + 1]));
        asm("v_cvt_pk_bf16_f32 %0, %1, %2" : "=v"(w1) : "v"(pe[8 * kc + 2]), "v"(pe[8 * kc + 3]));
        asm("v_cvt_pk_bf16_f32 %0, %1, %2" : "=v"(u0) : "v"(pe[8 * kc + 4]), "v"(pe[8 * kc + 5]));
        asm("v_cvt_pk_bf16_f32 %0, %1, %2" : "=v"(u1) : "v"(pe[8 * kc + 6]), "v"(pe[8 * kc + 7]));
        // dst.hi31:63 <-> src.lo0:31: yields (d0,d2) and (d1,d3) of the A-frag
        asm("v_permlane32_swap_b32 %0, %1" : "+v"(w0), "+v"(u0));
        asm("v_permlane32_swap_b32 %0, %1" : "+v"(w1), "+v"(u1));
        const u32x4 pd = {w0, w1, u0, u1};
        pa[kt * 2 + kc] = __builtin_bit_cast(bf16x8, pd);
      }
    }

    // ---- PV: O[q][d] += P * V, 4 k-chunks x 4 d-tiles, ILP 4 ----
#pragma unroll
    for (int c4 = 0; c4 < 4; ++c4) {
      const int byt = (c4 * 32) ^ cswz;
#pragma unroll
      for (int dt = 0; dt < 4; ++dt) {
        const bf16x8 vf = *reinterpret_cast<const bf16x8*>(vb + (dt * 32 + rl) * 128 + byt);
        o[dt] = __builtin_amdgcn_mfma_f32_32x32x16_bf16(pa[c4], vf, o[dt], 0, 0, 0);
      }
    }
  }

  // L[q]: lanes l and l+32 hold complementary k-subsets of the same q
  const float lt = lsum + __shfl_xor(lsum, 32);
  if (hi == 0) Lp[(size_t)split * NN + qw + rl] = lt;

  float* Ob = Op + (size_t)split * NN * DD;
#pragma unroll
  for (int dt = 0; dt < 4; ++dt)
#pragma unroll
    for (int r = 0; r < 16; ++r) {
      const int q = (r & 3) + 8 * (r >> 2) + 4 * hi;
      Ob[(size_t)(qw + q) * DD + dt * 32 + rl] = o[dt][r];
    }
}

// K3: combine splits, y = 1.5x - 0.5*(O/L), LayerNorm over D, write fp32 out.
__global__ void k_final(const float* __restrict__ x, const float* __restrict__ gamma,
                        const float* __restrict__ beta, const float* __restrict__ Op,
                        const float* __restrict__ Lp, float* __restrict__ out, int nsplit) {
  const int wave = threadIdx.x >> 6, lane = threadIdx.x & 63;
  const int row = blockIdx.x * 4 + wave;
  float o0 = 0.f, o1 = 0.f, lt = 0.f;
  for (int s = 0; s < nsplit; ++s) {
    const float2 v = *reinterpret_cast<const float2*>(
        Op + (size_t)s * NN * DD + (size_t)row * DD + 2 * lane);
    o0 += v.x;
    o1 += v.y;
    lt += Lp[(size_t)s * NN + row];
  }
  const float inv = 1.0f / lt;
  const float2 xv = *reinterpret_cast<const float2*>(x + (size_t)row * DD + 2 * lane);
  float y0 = 1.5f * xv.x - 0.5f * o0 * inv;
  float y1 = 1.5f * xv.y - 0.5f * o1 * inv;
  float sum = y0 + y1;
#pragma unroll
  for (int m = 1; m < 64; m <<= 1) sum += __shfl_xor(sum, m);
  const float mu = sum * (1.0f / 128.0f);
  const float d0 = y0 - mu, d1 = y1 - mu;
  float vs = d0 * d0 + d1 * d1;
#pragma unroll
  for (int m = 1; m < 64; m <<= 1) vs += __shfl_xor(vs, m);
  const float rs = rsqrtf(vs * (1.0f / 128.0f) + 1e-5f);
  const float2 g = *reinterpret_cast<const float2*>(gamma + 2 * lane);
  const float2 b = *reinterpret_cast<const float2*>(beta + 2 * lane);
  float2 ov;
  ov.x = d0 * rs * g.x + b.x;
  ov.y = d1 * rs * g.y + b.y;
  *reinterpret_cast<float2*>(out + (size_t)row * DD + 2 * lane) = ov;
}

extern "C" void kernel_launch(void* const* d_in, const int* in_sizes, int n_in,
                              void* d_out, int out_size, void* d_ws, size_t ws_size,
                              hipStream_t stream) {
  const float* x = (const float*)d_in[0];
  const float* gamma = (const float*)d_in[1];
  const float* beta = (const float*)d_in[2];
  float* out = (float*)d_out;
  char* ws = (char*)d_ws;

  uint16_t* nx = (uint16_t*)ws;                            // 4 MiB bf16 [N][D]
  uint16_t* xT = (uint16_t*)(ws + (size_t)NN * DD * 2);    // 4 MiB bf16 [D][N]
  const size_t base = (size_t)2 * NN * DD * 2;
  const size_t per = (size_t)NN * DD * 4 + (size_t)NN * 4; // per-split O + L

  int nsplit = 1;
  if (ws_size >= base + 4 * per) nsplit = 4;
  else if (ws_size >= base + 2 * per) nsplit = 2;

  float* Op = (float*)(ws + base);
  float* Lp = (float*)(ws + base + (size_t)nsplit * NN * DD * 4);

  k_norm<<<NN / 4, 256, 0, stream>>>(x, nx);
  k_transpose<<<(NN / 64) * (DD / 64), 256, 0, stream>>>(x, xT);
  k_attn<<<dim3((NN / QB) * nsplit), 512, 0, stream>>>(nx, xT, Op, Lp, nsplit);
  k_final<<<NN / 4, 256, 0, stream>>>(x, gamma, beta, Op, Lp, out, nsplit);
}

// Round 3
// 133.079 us; speedup vs baseline: 1.2752x; 1.1955x over previous
//
#include <hip/hip_runtime.h>
#include <stdint.h>

#define NN 16384
#define DD 128
#define KT 64      // k-tile rows
#define QB 128     // q rows per block (4 waves x 32)

typedef float f32x16 __attribute__((ext_vector_type(16)));
typedef long long i64;

using gv = __attribute__((address_space(1))) const void;
using lv = __attribute__((address_space(3))) void;

// K1: row L2-norms -> nx fp8 (e4m3), scaled by sqrt(log2(e)) so that
// QK^T dot products come out pre-multiplied by log2(e) -> softmax is a
// bare v_exp_f32 (2^x). One wave per row, 2 cols/lane.
__global__ void k_norm(const float* __restrict__ x, uint8_t* __restrict__ nx) {
  const int wave = threadIdx.x >> 6, lane = threadIdx.x & 63;
  const int row = blockIdx.x * 4 + wave;
  const float2 v = *reinterpret_cast<const float2*>(x + (size_t)row * DD + 2 * lane);
  float ss = v.x * v.x + v.y * v.y;
#pragma unroll
  for (int m = 1; m < 64; m <<= 1) ss += __shfl_xor(ss, m);
  const float rn = 1.2011224087f / fmaxf(sqrtf(ss), 1e-12f);  // sqrt(log2 e)/|x|
  const int w = __builtin_amdgcn_cvt_pk_fp8_f32(v.x * rn, v.y * rn, 0, false);
  *reinterpret_cast<uint16_t*>(nx + (size_t)row * DD + 2 * lane) = (uint16_t)w;
}

// K1b: transpose x (fp32 [N][D]) -> xT (fp8 [D][N]) via LDS tile.
__global__ void k_transpose(const float* __restrict__ x, uint8_t* __restrict__ xT) {
  __shared__ uint16_t tile[64 * 66];  // 64 n-rows x 128 d fp8, row stride 132B
  const int n0 = blockIdx.x * 64;
  const int t = threadIdx.x;
#pragma unroll
  for (int e = 0; e < 16; ++e) {
    const int idx = e * 256 + t;
    const int r = idx >> 6, c2 = idx & 63;
    const float2 v = *reinterpret_cast<const float2*>(x + (size_t)(n0 + r) * DD + 2 * c2);
    const int w = __builtin_amdgcn_cvt_pk_fp8_f32(v.x, v.y, 0, false);
    tile[r * 66 + c2] = (uint16_t)w;
  }
  __syncthreads();
  const uint8_t* t8 = reinterpret_cast<const uint8_t*>(tile);
#pragma unroll
  for (int e = 0; e < 8; ++e) {
    const int idx = e * 256 + t;
    const int d = idx >> 4, n4 = (idx & 15) << 2;
    uint32_t w = (uint32_t)t8[(n4 + 0) * 132 + d];
    w |= (uint32_t)t8[(n4 + 1) * 132 + d] << 8;
    w |= (uint32_t)t8[(n4 + 2) * 132 + d] << 16;
    w |= (uint32_t)t8[(n4 + 3) * 132 + d] << 24;
    *reinterpret_cast<uint32_t*>(xT + (size_t)d * NN + n0 + n4) = w;
  }
}

// K2: flash attention, 4 waves x 32 q-rows, fp8 32x32x16 MFMA, swapped QK^T,
// in-register softmax (|s|<=log2e -> no max tracking), P packed to fp8 via
// cvt_pk_fp8 + permlane32_swap. 3-buffer staging, counted vmcnt, 3 blocks/CU.
__global__ __launch_bounds__(256, 3) void k_attn(
    const uint8_t* __restrict__ nx, const uint8_t* __restrict__ xT,
    float* __restrict__ Op, float* __restrict__ Lp, int nsplit) {
  __shared__ alignas(16) uint8_t Kb[3][KT * DD];   // 3 x 8KB, rows 128B, swz bits4-6
  __shared__ alignas(16) uint8_t Vb[3][DD * KT];   // 3 x 8KB, V^T rows 64B, swz bits4-5

  const int tid = threadIdx.x;
  const int wave = tid >> 6;
  const int lane = tid & 63;
  const int rl = lane & 31;
  const int hi = lane >> 5;
  const int swzk = (rl & 7) << 4;
  const int swzv = ((rl >> 1) & 3) << 4;

  // XCD-grouped decomposition: blocks of one split land on 8/nsplit XCDs
  // so the split's K/V slice stays L2-resident.
  const int id = blockIdx.x;
  const int gs = 8 / nsplit;
  const int split = (id & 7) / gs;
  const int qblock = (id >> 3) * gs + (id & (gs - 1));

  const int nt = (NN / KT) / nsplit;
  const int t0s = split * nt;
  const int qw = qblock * QB + wave * 32;

  // Q B-frags (fp8): col q = l&31, d-elements dc*16 + 8*hi .. +8
  i64 q8[8];
#pragma unroll
  for (int dc = 0; dc < 8; ++dc)
    q8[dc] = *reinterpret_cast<const i64*>(nx + (size_t)(qw + rl) * DD + dc * 16 + 8 * hi);

  f32x16 o[4];
#pragma unroll
  for (int dt = 0; dt < 4; ++dt)
#pragma unroll
    for (int r = 0; r < 16; ++r) o[dt][r] = 0.f;
  float lsum = 0.f;

  // Stage K-tile [64][128]fp8 and V^T-tile [128][64]fp8: linear LDS dest,
  // inverse-swizzled global source (both-sides-or-neither).
  auto stage = [&](int tt, int buf) {
    const int k0 = tt * KT;
#pragma unroll
    for (int jj = 0; jj < 2; ++jj) {
      const int j = wave * 2 + jj;
      const int A = j * 1024 + lane * 16;
      {
        const int row = A >> 7, b = A & 127;
        const uint8_t* src = nx + (size_t)(k0 + row) * DD + (b ^ ((row & 7) << 4));
        __builtin_amdgcn_global_load_lds((gv*)src,
            (lv*)(&Kb[buf][0] + j * 1024), 16, 0, 0);
      }
      {
        const int d = A >> 6, b2 = A & 63;
        const uint8_t* src = xT + (size_t)d * NN + k0 + (b2 ^ (((d >> 1) & 3) << 4));
        __builtin_amdgcn_global_load_lds((gv*)src,
            (lv*)(&Vb[buf][0] + j * 1024), 16, 0, 0);
      }
    }
  };

  stage(t0s + 0, 0);
  stage(t0s + 1, 1);

  for (int t = 0; t < nt; ++t) {
    __builtin_amdgcn_sched_barrier(0);
    if (t + 1 < nt) asm volatile("s_waitcnt vmcnt(4)" ::: "memory");
    else            asm volatile("s_waitcnt vmcnt(0)" ::: "memory");
    __builtin_amdgcn_s_barrier();
    __builtin_amdgcn_sched_barrier(0);
    if (t + 2 < nt) stage(t0s + t + 2, (t + 2) % 3);

    const int buf = t % 3;
    const uint8_t* kb = &Kb[buf][0];
    const uint8_t* vb = &Vb[buf][0];

    // ---- swapped QK^T: S^T[k][q], two 32-row k-subtiles ----
    f32x16 s0, s1;
#pragma unroll
    for (int r = 0; r < 16; ++r) { s0[r] = 0.f; s1[r] = 0.f; }
    __builtin_amdgcn_s_setprio(1);
#pragma unroll
    for (int dc = 0; dc < 8; ++dc) {
      const int byt = (dc * 16 + 8 * hi) ^ swzk;
      const i64 ka0 = __builtin_bit_cast(i64, *reinterpret_cast<const uint2*>(kb + rl * 128 + byt));
      const i64 ka1 = __builtin_bit_cast(i64, *reinterpret_cast<const uint2*>(kb + 4096 + rl * 128 + byt));
      s0 = __builtin_amdgcn_mfma_f32_32x32x16_fp8_fp8(ka0, q8[dc], s0, 0, 0, 0);
      s1 = __builtin_amdgcn_mfma_f32_32x32x16_fp8_fp8(ka1, q8[dc], s1, 0, 0, 0);
    }
    __builtin_amdgcn_s_setprio(0);

    // ---- softmax: p = 2^s (s pre-scaled by log2 e; |s|<=1.45, no max),
    //      row-sum partials, pack P to fp8 A-frags via permlane32_swap ----
    // lane holds P[q=l&31][k_local=(r&3)+8*(r>>2)+4*hi+32*kt]
    i64 pa[4];
#pragma unroll
    for (int kt = 0; kt < 2; ++kt) {
      float pe[16];
#pragma unroll
      for (int r = 0; r < 16; ++r) {
        const float sv = (kt == 0) ? s0[r] : s1[r];
        float p;
        asm("v_exp_f32 %0, %1" : "=v"(p) : "v"(sv));
        pe[r] = p;
        lsum += p;
      }
#pragma unroll
      for (int kc = 0; kc < 2; ++kc) {
        uint32_t wlo = (uint32_t)__builtin_amdgcn_cvt_pk_fp8_f32(pe[8 * kc + 0], pe[8 * kc + 1], 0, false);
        wlo = (uint32_t)__builtin_amdgcn_cvt_pk_fp8_f32(pe[8 * kc + 2], pe[8 * kc + 3], (int)wlo, true);
        uint32_t whi = (uint32_t)__builtin_amdgcn_cvt_pk_fp8_f32(pe[8 * kc + 4], pe[8 * kc + 5], 0, false);
        whi = (uint32_t)__builtin_amdgcn_cvt_pk_fp8_f32(pe[8 * kc + 6], pe[8 * kc + 7], (int)whi, true);
        // swap wlo[hi-lanes] <-> whi[lo-lanes]: frag = (wlo, whi) = k bytes 0..7
        asm("v_permlane32_swap_b32 %0, %1" : "+v"(wlo), "+v"(whi));
        const uint2 pd = {wlo, whi};
        pa[kt * 2 + kc] = __builtin_bit_cast(i64, pd);
      }
    }

    // ---- PV: O[q][d] += P * V ----
    __builtin_amdgcn_s_setprio(1);
#pragma unroll
    for (int c4 = 0; c4 < 4; ++c4) {
      const int cb = (c4 * 16 + 8 * hi) ^ swzv;
#pragma unroll
      for (int dt = 0; dt < 4; ++dt) {
        const i64 vf = __builtin_bit_cast(i64,
            *reinterpret_cast<const uint2*>(vb + (dt * 32 + rl) * 64 + cb));
        o[dt] = __builtin_amdgcn_mfma_f32_32x32x16_fp8_fp8(pa[c4], vf, o[dt], 0, 0, 0);
      }
    }
    __builtin_amdgcn_s_setprio(0);
  }

  // L[q]: lanes l and l+32 hold complementary k-subsets of the same q
  const float lt = lsum + __shfl_xor(lsum, 32);
  if (hi == 0) Lp[(size_t)split * NN + qw + rl] = lt;

  float* Ob = Op + (size_t)split * NN * DD;
#pragma unroll
  for (int dt = 0; dt < 4; ++dt)
#pragma unroll
    for (int r = 0; r < 16; ++r) {
      const int q = (r & 3) + 8 * (r >> 2) + 4 * hi;
      Ob[(size_t)(qw + q) * DD + dt * 32 + rl] = o[dt][r];
    }
}

// K3: combine splits, y = 1.5x - 0.5*(O/L), LayerNorm over D, write fp32 out.
__global__ void k_final(const float* __restrict__ x, const float* __restrict__ gamma,
                        const float* __restrict__ beta, const float* __restrict__ Op,
                        const float* __restrict__ Lp, float* __restrict__ out, int nsplit) {
  const int wave = threadIdx.x >> 6, lane = threadIdx.x & 63;
  const int row = blockIdx.x * 4 + wave;
  float o0 = 0.f, o1 = 0.f, lt = 0.f;
  for (int s = 0; s < nsplit; ++s) {
    const float2 v = *reinterpret_cast<const float2*>(
        Op + (size_t)s * NN * DD + (size_t)row * DD + 2 * lane);
    o0 += v.x;
    o1 += v.y;
    lt += Lp[(size_t)s * NN + row];
  }
  const float inv = 1.0f / lt;
  const float2 xv = *reinterpret_cast<const float2*>(x + (size_t)row * DD + 2 * lane);
  float y0 = 1.5f * xv.x - 0.5f * o0 * inv;
  float y1 = 1.5f * xv.y - 0.5f * o1 * inv;
  float sum = y0 + y1;
#pragma unroll
  for (int m = 1; m < 64; m <<= 1) sum += __shfl_xor(sum, m);
  const float mu = sum * (1.0f / 128.0f);
  const float d0 = y0 - mu, d1 = y1 - mu;
  float vs = d0 * d0 + d1 * d1;
#pragma unroll
  for (int m = 1; m < 64; m <<= 1) vs += __shfl_xor(vs, m);
  const float rs = rsqrtf(vs * (1.0f / 128.0f) + 1e-5f);
  const float2 g = *reinterpret_cast<const float2*>(gamma + 2 * lane);
  const float2 b = *reinterpret_cast<const float2*>(beta + 2 * lane);
  float2 ov;
  ov.x = d0 * rs * g.x + b.x;
  ov.y = d1 * rs * g.y + b.y;
  *reinterpret_cast<float2*>(out + (size_t)row * DD + 2 * lane) = ov;
}

extern "C" void kernel_launch(void* const* d_in, const int* in_sizes, int n_in,
                              void* d_out, int out_size, void* d_ws, size_t ws_size,
                              hipStream_t stream) {
  const float* x = (const float*)d_in[0];
  const float* gamma = (const float*)d_in[1];
  const float* beta = (const float*)d_in[2];
  float* out = (float*)d_out;
  char* ws = (char*)d_ws;

  uint8_t* nx = (uint8_t*)ws;                           // 2 MiB fp8 [N][D], scaled
  uint8_t* xT = (uint8_t*)(ws + (size_t)NN * DD);       // 2 MiB fp8 [D][N]
  const size_t base = (size_t)2 * NN * DD;
  const size_t per = (size_t)NN * DD * 4 + (size_t)NN * 4;  // per-split O + L

  int nsplit = 1;
  if (ws_size >= base + 4 * per) nsplit = 4;
  else if (ws_size >= base + 2 * per) nsplit = 2;

  float* Op = (float*)(ws + base);
  float* Lp = (float*)(ws + base + (size_t)nsplit * NN * DD * 4);

  k_norm<<<NN / 4, 256, 0, stream>>>(x, nx);
  k_transpose<<<NN / 64, 256, 0, stream>>>(x, xT);
  k_attn<<<dim3((NN / QB) * nsplit), 256, 0, stream>>>(nx, xT, Op, Lp, nsplit);
  k_final<<<NN / 4, 256, 0, stream>>>(x, gamma, beta, Op, Lp, out, nsplit);
}